// Round 21
// baseline (1216.086 us; speedup 1.0000x reference)
//
#include <hip/hip_runtime.h>

#define NB 32
#define NC 32
#define NNODE 512
#define NT 168
#define NTO 156
#define NQ 39          // NTO / 4
#define NEMB 40
#define KNEI 20
#define NADJ 21        // 20 neighbors + diagonal
#define ZT_PITCH 42    // 21-dword stride -> conflict-free LDS scatter/reads
#define XROWS 176      // padded t rows in xbf
#define NPB 4          // nodes per conv block
#define CT (NC * NTO)      // 4992 elements per (b,v) slab
#define NPAIR (CT / 8)     // 624 ushort8 pairs

static_assert(NTO == 4 * NQ, "t quads");

typedef __attribute__((ext_vector_type(8))) short bf16x8;
typedef __attribute__((ext_vector_type(16))) float f32x16;
typedef __attribute__((ext_vector_type(4))) float f32x4;
typedef __attribute__((ext_vector_type(8))) unsigned short u16x8;
typedef __attribute__((ext_vector_type(4))) unsigned short u16x4;

// ---------------------------------------------------------------- helpers
__device__ __forceinline__ float fast_tanh(float x) {
  float e = __expf(2.0f * x);
  return 1.0f - 2.0f / (e + 1.0f);
}
__device__ __forceinline__ float fast_sigmoid(float x) {
  return 1.0f / (1.0f + __expf(-x));
}
__device__ __forceinline__ unsigned short f2b(float v) {   // f32 -> bf16 RNE
  unsigned int u = __float_as_uint(v);
  unsigned int r = (u + 0x7FFFu + ((u >> 16) & 1u)) >> 16;
  return (unsigned short)r;
}
__device__ __forceinline__ float b2f(unsigned short u) {
  return __uint_as_float((unsigned int)u << 16);
}
template <typename T>
__device__ __forceinline__ void pin(T& v) {
  f32x4 t = __builtin_bit_cast(f32x4, v);
  asm volatile("" : "+v"(t));
  v = __builtin_bit_cast(T, t);
}

// ---------------------------------------------------------------- G1: node embeddings
__global__ __launch_bounds__(128) void g1_kernel(
    const float* __restrict__ emb1, const float* __restrict__ emb2,
    const float* __restrict__ W1, const float* __restrict__ b1,
    const float* __restrict__ W2, const float* __restrict__ b2,
    const int* __restrict__ idx, float* __restrict__ n1, float* __restrict__ n2) {
  const int v = blockIdx.x;
  const int tid = threadIdx.x;
  const int iv = idx[v];
  if (tid < NEMB) {
    float s = b1[tid];
    const float* er = emb1 + iv * NEMB;
    const float* wr = W1 + tid * NEMB;
    for (int f = 0; f < NEMB; ++f) s = fmaf(er[f], wr[f], s);
    n1[v * NEMB + tid] = tanhf(3.0f * s);
  } else if (tid >= 64 && tid < 64 + NEMB) {
    const int e = tid - 64;
    float s = b2[e];
    const float* er = emb2 + iv * NEMB;
    const float* wr = W2 + e * NEMB;
    for (int f = 0; f < NEMB; ++f) s = fmaf(er[f], wr[f], s);
    n2[v * NEMB + e] = tanhf(3.0f * s);
  }
}

// ---------------------------------------------------------------- G2: adjacency row + topk + normalize
__global__ __launch_bounds__(256) void g2_kernel(
    const float* __restrict__ n1, const float* __restrict__ n2,
    int* __restrict__ cols, float* __restrict__ wts) {
  const int v = blockIdx.x;
  const int tid = threadIdx.x;
  volatile __shared__ float Arow[NNODE];
  __shared__ float n1v[NEMB], n2v[NEMB];
  if (tid < NEMB) n1v[tid] = n1[v * NEMB + tid];
  if (tid >= 64 && tid < 64 + NEMB) n2v[tid - 64] = n2[v * NEMB + tid - 64];
  __syncthreads();
  for (int w = tid; w < NNODE; w += 256) {
    float d1 = 0.f, d2 = 0.f;
    const float* r1 = n1 + w * NEMB;
    const float* r2 = n2 + w * NEMB;
    for (int e = 0; e < NEMB; ++e) {
      d1 = fmaf(n1v[e], r2[e], d1);
      d2 = fmaf(n2v[e], r1[e], d2);
    }
    float a = tanhf(3.0f * (d1 - d2));
    Arow[w] = a > 0.f ? a : 0.f;
  }
  __syncthreads();
  if (tid >= 64) return;   // single wave does topk
  float sum = 1.0f;        // diagonal of A+I
  float selv[KNEI];
  int seli[KNEI];
  #pragma unroll
  for (int s = 0; s < KNEI; ++s) {
    float bv = -1.f; int bi = NNODE;
    #pragma unroll
    for (int w8 = 0; w8 < NNODE / 64; ++w8) {
      const int w = tid + 64 * w8;
      const float val = Arow[w];
      if (val > bv || (val == bv && w < bi)) { bv = val; bi = w; }
    }
    #pragma unroll
    for (int off = 32; off >= 1; off >>= 1) {
      const float ov = __shfl_down(bv, off);
      const int oi = __shfl_down(bi, off);
      if (ov > bv || (ov == bv && oi < bi)) { bv = ov; bi = oi; }
    }
    bv = __shfl(bv, 0);
    bi = __shfl(bi, 0);
    selv[s] = bv;
    seli[s] = bi;
    Arow[bi] = -2.f;
    sum += bv;
  }
  if (tid == 0) {
    const float inv = 1.0f / sum;
    #pragma unroll
    for (int s = 0; s < KNEI; ++s) {
      cols[v * NADJ + s] = seli[s];
      wts[v * NADJ + s] = selv[s] * inv;
    }
    cols[v * NADJ + KNEI] = v;
    wts[v * NADJ + KNEI] = inv;
  }
}

// ---------------------------------------------------------------- weights struct
struct ZParams {
  const float* fw[4]; const float* fb[4];
  const float* gw[4]; const float* gb[4];
};

// ---------------------------------------------------------------- pack: conv A-frags + bias + N-mat A-frags (16x16 layout)
#define PA_CNT (2 * 2 * 7 * 64 * 8)
#define PB_CNT (2 * 64 * 16)
#define PNA_CNT (3 * 2 * 64 * 8)
__global__ __launch_bounds__(256) void pack_kernel(ZParams p, const float* __restrict__ mw,
                                                   unsigned short* __restrict__ pA,
                                                   float* __restrict__ pB,
                                                   unsigned short* __restrict__ pNA) {
  const int idx = blockIdx.x * 256 + threadIdx.x;
  if (idx < PA_CNT) {
    const int e = idx & 7;
    const int l = (idx >> 3) & 63;
    int rest = idx >> 9;
    const int j = rest % 7;
    rest /= 7;
    const int s = rest & 1;
    const int m = rest >> 1;
    const int row = l & 31;
    const int k = ((l >> 5) << 3) + e;
    const int ci = s * 16 + k;
    const int isF = (row < 16);
    const int co = m * 16 + (isF ? row : row - 16);
    const int br = co >> 3;
    const int kk = (br == 0) ? 2 : (br == 1) ? 3 : (br == 2) ? 6 : 7;
    const int jw = j - (7 - kk);
    const float* arr = isF ? p.fw[br] : p.gw[br];
    float val = (jw >= 0) ? arr[((co & 7) * NC + ci) * kk + jw] : 0.f;
    pA[idx] = f2b(val);
  } else if (idx < PA_CNT + PB_CNT) {
    const int ib = idx - PA_CNT;
    const int r = ib & 15;
    const int l = (ib >> 4) & 63;
    const int m = ib >> 10;
    const int rr = r & 7;
    const int row = (rr & 3) + 8 * (rr >> 2) + 4 * (l >> 5);
    const int co = m * 16 + row;
    const int br = co >> 3;
    const float* arr = (r < 8) ? p.fb[br] : p.gb[br];
    pB[ib] = arr[co & 7];
  } else if (idx < PA_CNT + PB_CNT + PNA_CNT) {
    // pNA16: [which(3)][cotile(2)][lane(64)][e(8)] bf16
    // 16x16x32 A-frag: lane l holds N[co = ct*16 + (l&15)][c = (l>>4)*8 + e]
    const int in_ = idx - (PA_CNT + PB_CNT);
    const int e = in_ & 7;
    const int l = (in_ >> 3) & 63;
    const int ct = (in_ >> 9) & 1;
    const int which = in_ >> 10;
    const int co = ct * 16 + (l & 15);
    const int c = ((l >> 4) << 3) + e;
    const float w0 = mw[co * 96 + c];
    const float w1 = mw[co * 96 + 32 + c];
    const float w2 = mw[co * 96 + 64 + c];
    float val;
    if (which == 0)      val = w0 + 0.05f * (w1 + w2);
    else if (which == 1) val = 0.95f * w1 + 0.0475f * w2;
    else                 val = 0.9025f * w2;
    pNA[in_] = f2b(val);
  }
}

// ---------------------------------------------------------------- XP: x (f32 [b][c][n][t]) -> xbf (bf16 [b][n][t(176)][c])
__global__ __launch_bounds__(256) void xprep_kernel(
    const float* __restrict__ x, unsigned short* __restrict__ xbf) {
  const int n = blockIdx.x;
  const int b = blockIdx.y;
  const int tid = threadIdx.x;
  const int cp = tid & 15;           // c-pair index (c = 2cp, 2cp+1)
  const int t0 = tid >> 4;           // 0..15
  const float* xc0 = x + ((size_t)(b * NC + 2 * cp) * NNODE + n) * NT;
  const float* xc1 = xc0 + (size_t)NNODE * NT;
  unsigned int* dst = (unsigned int*)(xbf + (size_t)(b * NNODE + n) * (XROWS * NC));
  #pragma unroll
  for (int k = 0; k < 11; ++k) {
    const int t = t0 + 16 * k;
    unsigned int v = 0;
    if (t < NT) {
      v = (unsigned int)f2b(xc0[t]) | ((unsigned int)f2b(xc1[t]) << 16);
    }
    dst[t * 16 + cp] = v;
  }
}

// ---------------------------------------------------------------- CONV: gated inception conv -> z[b][v][t][c] bf16
// double-buffered zt: ONE barrier per node (copy(nn) overlaps phase1(nn+1))
__attribute__((amdgpu_waves_per_eu(2)))
__global__ __launch_bounds__(256) void conv_kernel(
    const unsigned short* __restrict__ xbf, const unsigned short* __restrict__ pA,
    const float* __restrict__ pBias, unsigned short* __restrict__ z) {
  __shared__ unsigned short zt0[NTO * ZT_PITCH];   // 13.1 KB
  __shared__ unsigned short zt1[NTO * ZT_PITCH];   // 13.1 KB
  const int n0 = blockIdx.x * NPB;
  const int b = blockIdx.y;
  const int tid = threadIdx.x;
  const int w = tid >> 6, l = tid & 63;
  const int jc = l & 31, h = l >> 5;
  const int m = w & 1;

  bf16x8 aF[2][7];
  #pragma unroll
  for (int s = 0; s < 2; ++s)
    #pragma unroll
    for (int j = 0; j < 7; ++j) {
      aF[s][j] = *reinterpret_cast<const bf16x8*>(
          pA + ((((m * 2 + s) * 7 + j) << 6) + l) * 8);
      pin(aF[s][j]);
    }
  f32x4 bias4[4];
  {
    const f32x4* pb4 = reinterpret_cast<const f32x4*>(pBias + (m * 64 + l) * 16);
    #pragma unroll
    for (int q = 0; q < 4; ++q) { bias4[q] = pb4[q]; pin(bias4[q]); }
  }

  #pragma unroll
  for (int nn = 0; nn < NPB; ++nn) {
    const int n = n0 + nn;
    unsigned short* zt = (nn & 1) ? zt1 : zt0;
    const unsigned short* xbn = xbf + (size_t)(b * NNODE + n) * (XROWS * NC);
    for (int tile = (w >> 1); tile < 5; tile += 2) {
      const int t0 = tile * 32;
      f32x16 acc;
      #pragma unroll
      for (int r = 0; r < 16; ++r) acc[r] = bias4[r >> 2][r & 3];
      const unsigned short* bp = xbn + (t0 + jc) * NC + h * 8;
      #pragma unroll
      for (int j = 0; j < 7; ++j) {
        bf16x8 b0 = *reinterpret_cast<const bf16x8*>(bp + 2 * j * NC);
        bf16x8 b1 = *reinterpret_cast<const bf16x8*>(bp + 2 * j * NC + 16);
        acc = __builtin_amdgcn_mfma_f32_32x32x16_bf16(aF[0][j], b0, acc, 0, 0, 0);
        acc = __builtin_amdgcn_mfma_f32_32x32x16_bf16(aF[1][j], b1, acc, 0, 0, 0);
      }
      const int t = t0 + jc;
      if (t < NTO) {
        #pragma unroll
        for (int r = 0; r < 8; ++r) {
          const float f = fast_tanh(acc[r]);
          const float g = fast_sigmoid(acc[r + 8]);
          const int row = (r & 3) + 8 * (r >> 2) + 4 * h;
          const int co = m * 16 + row;
          zt[t * ZT_PITCH + co] = f2b(f * g);
        }
      }
    }
    __syncthreads();   // phase1(nn) done (and, transitively, copy(nn-1) done)
    unsigned short* zv = z + (size_t)(b * NNODE + n) * CT;
    for (int i = tid; i < CT / 4; i += 256) {
      const int row = i >> 3, q = i & 7;
      ushort4 v4 = *reinterpret_cast<const ushort4*>(zt + row * ZT_PITCH + 4 * q);
      *reinterpret_cast<ushort4*>(zv + 4 * i) = v4;
    }
    // no second barrier: next phase1 writes the OTHER buffer
  }
}

// ---------------------------------------------------------------- HOP: dst = A_hat * src ; XCD-affine bid swizzle
__global__ __launch_bounds__(256) void hop_kernel(
    const unsigned short* __restrict__ src, const int* __restrict__ cols,
    const float* __restrict__ wts, unsigned short* __restrict__ dst) {
  const int bid = blockIdx.x;
  const int r = bid & 7;
  const int t_ = bid >> 3;
  const int v = t_ & (NNODE - 1);
  const int g = t_ >> 9;
  const int b = g * 8 + r;
  const int tid = threadIdx.x;
  float acc[3][8];
  #pragma unroll
  for (int k = 0; k < 3; ++k)
    #pragma unroll
    for (int j = 0; j < 8; ++j) acc[k][j] = 0.f;
  for (int s = 0; s < NADJ; ++s) {
    const int col = cols[v * NADJ + s];
    const float w = wts[v * NADJ + s];
    const unsigned short* p = src + ((size_t)(b << 9) + col) * CT;
    #pragma unroll
    for (int k = 0; k < 2; ++k) {
      u16x8 u = *reinterpret_cast<const u16x8*>(p + 8 * (tid + 256 * k));
      #pragma unroll
      for (int j = 0; j < 8; ++j) acc[k][j] = fmaf(w, b2f(u[j]), acc[k][j]);
    }
    if (tid < NPAIR - 512) {
      u16x8 u = *reinterpret_cast<const u16x8*>(p + 8 * (tid + 512));
      #pragma unroll
      for (int j = 0; j < 8; ++j) acc[2][j] = fmaf(w, b2f(u[j]), acc[2][j]);
    }
  }
  unsigned short* dp = dst + ((size_t)(b << 9) + v) * CT;
  #pragma unroll
  for (int k = 0; k < 2; ++k) {
    u16x8 o;
    #pragma unroll
    for (int j = 0; j < 8; ++j) o[j] = f2b(acc[k][j]);
    *reinterpret_cast<u16x8*>(dp + 8 * (tid + 256 * k)) = o;
  }
  if (tid < NPAIR - 512) {
    u16x8 o;
    #pragma unroll
    for (int j = 0; j < 8; ++j) o[j] = f2b(acc[2][j]);
    *reinterpret_cast<u16x8*>(dp + 8 * (tid + 512)) = o;
  }
}

// ---------------------------------------------------------------- FIN: P = N0*z + N1*g1 + N2*g2 + mb + x_bf16 ; stats
// 16x16x32 MFMA version: acc = 2x f32x4 (8 AGPRs vs 16) -> lower unified
// register pressure -> more resident waves. 10 strips of 16 t.
__global__ __launch_bounds__(256) void fin_kernel(
    const unsigned short* __restrict__ z, const unsigned short* __restrict__ g1,
    const unsigned short* __restrict__ g2, const unsigned short* __restrict__ xbf,
    const unsigned short* __restrict__ pNA, const float* __restrict__ mb,
    unsigned short* __restrict__ P, float* __restrict__ stats) {
  const int b = blockIdx.y;
  const int tid = threadIdx.x;
  const int w = tid >> 6, l = tid & 63;
  const int tl = l & 15;          // D col = t within strip
  const int oct = l >> 4;         // c-octet for B, co-quad for D
  const int v = blockIdx.x * 4 + w;

  bf16x8 nA[3][2];
  #pragma unroll
  for (int which = 0; which < 3; ++which)
    #pragma unroll
    for (int ct = 0; ct < 2; ++ct) {
      nA[which][ct] = *reinterpret_cast<const bf16x8*>(
          pNA + (((which * 2 + ct) << 6) + l) * 8);
      pin(nA[which][ct]);
    }
  // mb for this lane's 8 output rows: co = ct*16 + oct*4 + r
  float4 mb0 = *reinterpret_cast<const float4*>(mb + oct * 4);
  float4 mb1 = *reinterpret_cast<const float4*>(mb + 16 + oct * 4);

  const size_t base = (size_t)(b << 9) + v;
  const unsigned short* zs_ = z + base * CT;
  const unsigned short* g1s = g1 + base * CT;
  const unsigned short* g2s = g2 + base * CT;
  const unsigned short* xres = xbf + (size_t)(b * NNODE + v) * (XROWS * NC) + 12 * NC;
  unsigned short* Ps = P + base * CT;
  float st1 = 0.f, st2 = 0.f;

  #pragma unroll
  for (int strip = 0; strip < 10; ++strip) {
    const int t = strip * 16 + tl;
    const int off = t * NC + oct * 8;   // strip 9: t up to 159 reads past slab (masked cols)
    bf16x8 bz = *reinterpret_cast<const bf16x8*>(zs_ + off);
    bf16x8 bg1 = *reinterpret_cast<const bf16x8*>(g1s + off);
    bf16x8 bg2 = *reinterpret_cast<const bf16x8*>(g2s + off);
    f32x4 acc0 = {0.f, 0.f, 0.f, 0.f};
    f32x4 acc1 = {0.f, 0.f, 0.f, 0.f};
    acc0 = __builtin_amdgcn_mfma_f32_16x16x32_bf16(nA[0][0], bz, acc0, 0, 0, 0);
    acc1 = __builtin_amdgcn_mfma_f32_16x16x32_bf16(nA[0][1], bz, acc1, 0, 0, 0);
    acc0 = __builtin_amdgcn_mfma_f32_16x16x32_bf16(nA[1][0], bg1, acc0, 0, 0, 0);
    acc1 = __builtin_amdgcn_mfma_f32_16x16x32_bf16(nA[1][1], bg1, acc1, 0, 0, 0);
    acc0 = __builtin_amdgcn_mfma_f32_16x16x32_bf16(nA[2][0], bg2, acc0, 0, 0, 0);
    acc1 = __builtin_amdgcn_mfma_f32_16x16x32_bf16(nA[2][1], bg2, acc1, 0, 0, 0);
    if (t < NTO) {
      // residual: co = ct*16 + oct*4 + r, contiguous over r
      u16x4 xu0 = *reinterpret_cast<const u16x4*>(xres + t * NC + oct * 4);
      u16x4 xu1 = *reinterpret_cast<const u16x4*>(xres + t * NC + 16 + oct * 4);
      #pragma unroll
      for (int r = 0; r < 4; ++r) {
        const int co0 = oct * 4 + r;
        const float val0 = acc0[r] + (&mb0.x)[r] + b2f(xu0[r]);
        Ps[co0 * NTO + t] = f2b(val0);
        st1 += val0; st2 += val0 * val0;
        const int co1 = 16 + oct * 4 + r;
        const float val1 = acc1[r] + (&mb1.x)[r] + b2f(xu1[r]);
        Ps[co1 * NTO + t] = f2b(val1);
        st1 += val1; st2 += val1 * val1;
      }
    }
  }
  #pragma unroll
  for (int off = 32; off >= 1; off >>= 1) {
    st1 += __shfl_down(st1, off);
    st2 += __shfl_down(st2, off);
  }
  __shared__ float r1[4], r2[4];
  if ((tid & 63) == 0) { r1[w] = st1; r2[w] = st2; }
  __syncthreads();
  if (tid == 0) {   // b uniform per block
    atomicAdd(&stats[b * 2], r1[0] + r1[1] + r1[2] + r1[3]);
    atomicAdd(&stats[b * 2 + 1], r2[0] + r2[1] + r2[2] + r2[3]);
  }
}

// ---------------------------------------------------------------- LN: thread=(v,co,q), b INNER loop (lnw/lnb read once)
__global__ __launch_bounds__(256) void ln_kernel(
    const unsigned short* __restrict__ P, float* __restrict__ out,
    const float* __restrict__ lnw, const float* __restrict__ lnb,
    const int* __restrict__ idx, const float* __restrict__ stats) {
  const int i = blockIdx.x * 256 + threadIdx.x;   // over NNODE*NC*NQ
  const int q = i % NQ;
  const int r = i / NQ;
  const int co = r % NC;
  const int v = r / NC;
  const int iv = idx[v];
  const int lb = (co * NNODE + iv) * NTO + 4 * q;
  const float4 w = *reinterpret_cast<const float4*>(lnw + lb);
  const float4 bb = *reinterpret_cast<const float4*>(lnb + lb);
  const float invM = 1.0f / (float)(NC * NNODE * NTO);
  const int poff = (v * NC + co) * NTO + 4 * q;   // within-b P offset
  const int ooff = (co * NNODE + v) * NTO + 4 * q;
  for (int b = 0; b < NB; ++b) {
    const float mean = stats[b * 2] * invM;
    const float var = stats[b * 2 + 1] * invM - mean * mean;
    const float rs = rsqrtf(var + 1e-5f);
    ushort4 u = *reinterpret_cast<const ushort4*>(P + (size_t)b * (NNODE * CT) + poff);
    float4 o;
    o.x = (b2f(u.x) - mean) * rs * w.x + bb.x;
    o.y = (b2f(u.y) - mean) * rs * w.y + bb.y;
    o.z = (b2f(u.z) - mean) * rs * w.z + bb.z;
    o.w = (b2f(u.w) - mean) * rs * w.w + bb.w;
    *reinterpret_cast<float4*>(out + (size_t)b * (NC * NNODE * NTO) + ooff) = o;
  }
}

// ---------------------------------------------------------------- launch
extern "C" void kernel_launch(void* const* d_in, const int* in_sizes, int n_in,
                              void* d_out, int out_size, void* d_ws, size_t ws_size,
                              hipStream_t stream) {
  const float* x    = (const float*)d_in[0];
  const int*   idx  = (const int*)d_in[1];
  const float* emb1 = (const float*)d_in[2];
  const float* emb2 = (const float*)d_in[3];
  const float* W1   = (const float*)d_in[4];
  const float* b1   = (const float*)d_in[5];
  const float* W2   = (const float*)d_in[6];
  const float* b2   = (const float*)d_in[7];
  const float* mlp_w = (const float*)d_in[24];
  const float* mlp_b = (const float*)d_in[25];
  const float* ln_w = (const float*)d_in[26];
  const float* ln_b = (const float*)d_in[27];

  char* ws = (char*)d_ws;
  float* n1    = (float*)(ws);
  float* n2    = (float*)(ws + (128 << 10));
  int*   cols  = (int*)  (ws + (256 << 10));
  float* wts   = (float*)(ws + (320 << 10));
  float* stats = (float*)(ws + (384 << 10));
  unsigned short* pA = (unsigned short*)(ws + (400 << 10));    // 28,672 B
  float* pBias = (float*)(ws + (440 << 10));                   // 8,192 B
  unsigned short* pNA = (unsigned short*)(ws + (456 << 10));   // 6,144 B
  unsigned short* xbf = (unsigned short*)(ws + (512 << 10));   // 184.5 MB (live thru fin)
  const size_t xbf_elems = (size_t)NB * NNODE * XROWS * NC;
  const size_t slab_elems = (size_t)NB * NNODE * CT;           // 163 MB each
  unsigned short* z  = xbf + xbf_elems;
  unsigned short* g1 = z + slab_elems;
  unsigned short* g2 = g1 + slab_elems;
  unsigned short* P  = g2 + slab_elems;                        // separate 163 MB

  ZParams zp;
  for (int k = 0; k < 4; ++k) {
    zp.fw[k] = (const float*)d_in[8 + 2 * k];
    zp.fb[k] = (const float*)d_in[9 + 2 * k];
    zp.gw[k] = (const float*)d_in[16 + 2 * k];
    zp.gb[k] = (const float*)d_in[17 + 2 * k];
  }

  hipMemsetAsync(stats, 0, 2 * NB * sizeof(float), stream);
  g1_kernel<<<NNODE, 128, 0, stream>>>(emb1, emb2, W1, b1, W2, b2, idx, n1, n2);
  g2_kernel<<<NNODE, 256, 0, stream>>>(n1, n2, cols, wts);
  pack_kernel<<<76, 256, 0, stream>>>(zp, mlp_w, pA, pBias, pNA);
  xprep_kernel<<<dim3(NNODE, NB), 256, 0, stream>>>(x, xbf);
  conv_kernel<<<dim3(NNODE / NPB, NB), 256, 0, stream>>>(xbf, pA, pBias, z);
  hop_kernel<<<NB * NNODE, 256, 0, stream>>>(z, cols, wts, g1);
  hop_kernel<<<NB * NNODE, 256, 0, stream>>>(g1, cols, wts, g2);
  fin_kernel<<<dim3(NNODE / 4, NB), 256, 0, stream>>>(z, g1, g2, xbf, pNA, mlp_b,
                                                      P, stats);
  ln_kernel<<<NNODE * NC * NQ / 256, 256, 0, stream>>>(P, (float*)d_out, ln_w,
                                                       ln_b, idx, stats);
}

// Round 22
// 1168.336 us; speedup vs baseline: 1.0409x; 1.0409x over previous
//
#include <hip/hip_runtime.h>

#define NB 32
#define NC 32
#define NNODE 512
#define NT 168
#define NTO 156
#define NQ 39          // NTO / 4
#define NEMB 40
#define KNEI 20
#define NADJ 21        // 20 neighbors + diagonal
#define ZT_PITCH 42    // 21-dword stride -> conflict-free LDS scatter/reads
#define XROWS 176      // padded t rows in xbf
#define NPB 4          // nodes per conv block
#define CT (NC * NTO)      // 4992 elements per (b,v) slab
#define NPAIR (CT / 8)     // 624 ushort8 pairs

static_assert(NTO == 4 * NQ, "t quads");

typedef __attribute__((ext_vector_type(8))) short bf16x8;
typedef __attribute__((ext_vector_type(16))) float f32x16;
typedef __attribute__((ext_vector_type(4))) float f32x4;
typedef __attribute__((ext_vector_type(8))) unsigned short u16x8;
typedef __attribute__((ext_vector_type(4))) unsigned short u16x4;

// ---------------------------------------------------------------- helpers
__device__ __forceinline__ float fast_tanh(float x) {
  float e = __expf(2.0f * x);
  return 1.0f - 2.0f / (e + 1.0f);
}
__device__ __forceinline__ float fast_sigmoid(float x) {
  return 1.0f / (1.0f + __expf(-x));
}
__device__ __forceinline__ unsigned short f2b(float v) {   // f32 -> bf16 RNE
  unsigned int u = __float_as_uint(v);
  unsigned int r = (u + 0x7FFFu + ((u >> 16) & 1u)) >> 16;
  return (unsigned short)r;
}
__device__ __forceinline__ float b2f(unsigned short u) {
  return __uint_as_float((unsigned int)u << 16);
}
template <typename T>
__device__ __forceinline__ void pin(T& v) {
  f32x4 t = __builtin_bit_cast(f32x4, v);
  asm volatile("" : "+v"(t));
  v = __builtin_bit_cast(T, t);
}

// ---------------------------------------------------------------- G1: node embeddings
__global__ __launch_bounds__(128) void g1_kernel(
    const float* __restrict__ emb1, const float* __restrict__ emb2,
    const float* __restrict__ W1, const float* __restrict__ b1,
    const float* __restrict__ W2, const float* __restrict__ b2,
    const int* __restrict__ idx, float* __restrict__ n1, float* __restrict__ n2) {
  const int v = blockIdx.x;
  const int tid = threadIdx.x;
  const int iv = idx[v];
  if (tid < NEMB) {
    float s = b1[tid];
    const float* er = emb1 + iv * NEMB;
    const float* wr = W1 + tid * NEMB;
    for (int f = 0; f < NEMB; ++f) s = fmaf(er[f], wr[f], s);
    n1[v * NEMB + tid] = tanhf(3.0f * s);
  } else if (tid >= 64 && tid < 64 + NEMB) {
    const int e = tid - 64;
    float s = b2[e];
    const float* er = emb2 + iv * NEMB;
    const float* wr = W2 + e * NEMB;
    for (int f = 0; f < NEMB; ++f) s = fmaf(er[f], wr[f], s);
    n2[v * NEMB + e] = tanhf(3.0f * s);
  }
}

// ---------------------------------------------------------------- G2: adjacency row + topk + normalize
__global__ __launch_bounds__(256) void g2_kernel(
    const float* __restrict__ n1, const float* __restrict__ n2,
    int* __restrict__ cols, float* __restrict__ wts) {
  const int v = blockIdx.x;
  const int tid = threadIdx.x;
  volatile __shared__ float Arow[NNODE];
  __shared__ float n1v[NEMB], n2v[NEMB];
  if (tid < NEMB) n1v[tid] = n1[v * NEMB + tid];
  if (tid >= 64 && tid < 64 + NEMB) n2v[tid - 64] = n2[v * NEMB + tid - 64];
  __syncthreads();
  for (int w = tid; w < NNODE; w += 256) {
    float d1 = 0.f, d2 = 0.f;
    const float* r1 = n1 + w * NEMB;
    const float* r2 = n2 + w * NEMB;
    for (int e = 0; e < NEMB; ++e) {
      d1 = fmaf(n1v[e], r2[e], d1);
      d2 = fmaf(n2v[e], r1[e], d2);
    }
    float a = tanhf(3.0f * (d1 - d2));
    Arow[w] = a > 0.f ? a : 0.f;
  }
  __syncthreads();
  if (tid >= 64) return;   // single wave does topk
  float sum = 1.0f;        // diagonal of A+I
  float selv[KNEI];
  int seli[KNEI];
  #pragma unroll
  for (int s = 0; s < KNEI; ++s) {
    float bv = -1.f; int bi = NNODE;
    #pragma unroll
    for (int w8 = 0; w8 < NNODE / 64; ++w8) {
      const int w = tid + 64 * w8;
      const float val = Arow[w];
      if (val > bv || (val == bv && w < bi)) { bv = val; bi = w; }
    }
    #pragma unroll
    for (int off = 32; off >= 1; off >>= 1) {
      const float ov = __shfl_down(bv, off);
      const int oi = __shfl_down(bi, off);
      if (ov > bv || (ov == bv && oi < bi)) { bv = ov; bi = oi; }
    }
    bv = __shfl(bv, 0);
    bi = __shfl(bi, 0);
    selv[s] = bv;
    seli[s] = bi;
    Arow[bi] = -2.f;
    sum += bv;
  }
  if (tid == 0) {
    const float inv = 1.0f / sum;
    #pragma unroll
    for (int s = 0; s < KNEI; ++s) {
      cols[v * NADJ + s] = seli[s];
      wts[v * NADJ + s] = selv[s] * inv;
    }
    cols[v * NADJ + KNEI] = v;
    wts[v * NADJ + KNEI] = inv;
  }
}

// ---------------------------------------------------------------- weights struct
struct ZParams {
  const float* fw[4]; const float* fb[4];
  const float* gw[4]; const float* gb[4];
};

// ---------------------------------------------------------------- pack: conv A-frags + bias + N-mat A-frags
#define PA_CNT (2 * 2 * 7 * 64 * 8)
#define PB_CNT (2 * 64 * 16)
#define PNA_CNT (3 * 2 * 64 * 8)
__global__ __launch_bounds__(256) void pack_kernel(ZParams p, const float* __restrict__ mw,
                                                   unsigned short* __restrict__ pA,
                                                   float* __restrict__ pB,
                                                   unsigned short* __restrict__ pNA) {
  const int idx = blockIdx.x * 256 + threadIdx.x;
  if (idx < PA_CNT) {
    const int e = idx & 7;
    const int l = (idx >> 3) & 63;
    int rest = idx >> 9;
    const int j = rest % 7;
    rest /= 7;
    const int s = rest & 1;
    const int m = rest >> 1;
    const int row = l & 31;
    const int k = ((l >> 5) << 3) + e;
    const int ci = s * 16 + k;
    const int isF = (row < 16);
    const int co = m * 16 + (isF ? row : row - 16);
    const int br = co >> 3;
    const int kk = (br == 0) ? 2 : (br == 1) ? 3 : (br == 2) ? 6 : 7;
    const int jw = j - (7 - kk);
    const float* arr = isF ? p.fw[br] : p.gw[br];
    float val = (jw >= 0) ? arr[((co & 7) * NC + ci) * kk + jw] : 0.f;
    pA[idx] = f2b(val);
  } else if (idx < PA_CNT + PB_CNT) {
    const int ib = idx - PA_CNT;
    const int r = ib & 15;
    const int l = (ib >> 4) & 63;
    const int m = ib >> 10;
    const int rr = r & 7;
    const int row = (rr & 3) + 8 * (rr >> 2) + 4 * (l >> 5);
    const int co = m * 16 + row;
    const int br = co >> 3;
    const float* arr = (r < 8) ? p.fb[br] : p.gb[br];
    pB[ib] = arr[co & 7];
  } else if (idx < PA_CNT + PB_CNT + PNA_CNT) {
    const int in_ = idx - (PA_CNT + PB_CNT);
    const int e = in_ & 7;
    const int l = (in_ >> 3) & 63;
    const int s = (in_ >> 9) & 1;
    const int which = in_ >> 10;
    const int co = l & 31;
    const int c = s * 16 + ((l >> 5) << 3) + e;
    const float w0 = mw[co * 96 + c];
    const float w1 = mw[co * 96 + 32 + c];
    const float w2 = mw[co * 96 + 64 + c];
    float val;
    if (which == 0)      val = w0 + 0.05f * (w1 + w2);
    else if (which == 1) val = 0.95f * w1 + 0.0475f * w2;
    else                 val = 0.9025f * w2;
    pNA[in_] = f2b(val);
  }
}

// ---------------------------------------------------------------- XP: x (f32 [b][c][n][t]) -> xbf (bf16 [b][n][t(176)][c])
__global__ __launch_bounds__(256) void xprep_kernel(
    const float* __restrict__ x, unsigned short* __restrict__ xbf) {
  const int n = blockIdx.x;
  const int b = blockIdx.y;
  const int tid = threadIdx.x;
  const int cp = tid & 15;           // c-pair index (c = 2cp, 2cp+1)
  const int t0 = tid >> 4;           // 0..15
  const float* xc0 = x + ((size_t)(b * NC + 2 * cp) * NNODE + n) * NT;
  const float* xc1 = xc0 + (size_t)NNODE * NT;
  unsigned int* dst = (unsigned int*)(xbf + (size_t)(b * NNODE + n) * (XROWS * NC));
  #pragma unroll
  for (int k = 0; k < 11; ++k) {
    const int t = t0 + 16 * k;
    unsigned int v = 0;
    if (t < NT) {
      v = (unsigned int)f2b(xc0[t]) | ((unsigned int)f2b(xc1[t]) << 16);
    }
    dst[t * 16 + cp] = v;
  }
}

// ---------------------------------------------------------------- CONV: gated inception conv -> z[b][v][t][c] bf16
// double-buffered zt; m=0 tile (branches k=2,3) skips j<4: those A-frags are
// exactly zero (zero-padded taps), so 8 of 14 MFMAs + loads are no-ops.
__attribute__((amdgpu_waves_per_eu(2)))
__global__ __launch_bounds__(256) void conv_kernel(
    const unsigned short* __restrict__ xbf, const unsigned short* __restrict__ pA,
    const float* __restrict__ pBias, unsigned short* __restrict__ z) {
  __shared__ unsigned short zt0[NTO * ZT_PITCH];   // 13.1 KB
  __shared__ unsigned short zt1[NTO * ZT_PITCH];   // 13.1 KB
  const int n0 = blockIdx.x * NPB;
  const int b = blockIdx.y;
  const int tid = threadIdx.x;
  const int w = tid >> 6, l = tid & 63;
  const int jc = l & 31, h = l >> 5;
  const int m = w & 1;

  bf16x8 aF[2][7];
  #pragma unroll
  for (int s = 0; s < 2; ++s)
    #pragma unroll
    for (int j = 0; j < 7; ++j) {
      aF[s][j] = *reinterpret_cast<const bf16x8*>(
          pA + ((((m * 2 + s) * 7 + j) << 6) + l) * 8);
      pin(aF[s][j]);
    }
  f32x4 bias4[4];
  {
    const f32x4* pb4 = reinterpret_cast<const f32x4*>(pBias + (m * 64 + l) * 16);
    #pragma unroll
    for (int q = 0; q < 4; ++q) { bias4[q] = pb4[q]; pin(bias4[q]); }
  }

  #pragma unroll
  for (int nn = 0; nn < NPB; ++nn) {
    const int n = n0 + nn;
    unsigned short* zt = (nn & 1) ? zt1 : zt0;
    const unsigned short* xbn = xbf + (size_t)(b * NNODE + n) * (XROWS * NC);
    for (int tile = (w >> 1); tile < 5; tile += 2) {
      const int t0 = tile * 32;
      f32x16 acc;
      #pragma unroll
      for (int r = 0; r < 16; ++r) acc[r] = bias4[r >> 2][r & 3];
      const unsigned short* bp = xbn + (t0 + jc) * NC + h * 8;
      if (m) {   // branches k=6,7 need taps j=0..3; k=2,3 (m=0) have zeros there
        #pragma unroll
        for (int j = 0; j < 4; ++j) {
          bf16x8 b0 = *reinterpret_cast<const bf16x8*>(bp + 2 * j * NC);
          bf16x8 b1 = *reinterpret_cast<const bf16x8*>(bp + 2 * j * NC + 16);
          acc = __builtin_amdgcn_mfma_f32_32x32x16_bf16(aF[0][j], b0, acc, 0, 0, 0);
          acc = __builtin_amdgcn_mfma_f32_32x32x16_bf16(aF[1][j], b1, acc, 0, 0, 0);
        }
      }
      #pragma unroll
      for (int j = 4; j < 7; ++j) {
        bf16x8 b0 = *reinterpret_cast<const bf16x8*>(bp + 2 * j * NC);
        bf16x8 b1 = *reinterpret_cast<const bf16x8*>(bp + 2 * j * NC + 16);
        acc = __builtin_amdgcn_mfma_f32_32x32x16_bf16(aF[0][j], b0, acc, 0, 0, 0);
        acc = __builtin_amdgcn_mfma_f32_32x32x16_bf16(aF[1][j], b1, acc, 0, 0, 0);
      }
      const int t = t0 + jc;
      if (t < NTO) {
        #pragma unroll
        for (int r = 0; r < 8; ++r) {
          const float f = fast_tanh(acc[r]);
          const float g = fast_sigmoid(acc[r + 8]);
          const int row = (r & 3) + 8 * (r >> 2) + 4 * h;
          const int co = m * 16 + row;
          zt[t * ZT_PITCH + co] = f2b(f * g);
        }
      }
    }
    __syncthreads();   // phase1(nn) done (and, transitively, copy(nn-1) done)
    unsigned short* zv = z + (size_t)(b * NNODE + n) * CT;
    for (int i = tid; i < CT / 4; i += 256) {
      const int row = i >> 3, q = i & 7;
      ushort4 v4 = *reinterpret_cast<const ushort4*>(zt + row * ZT_PITCH + 4 * q);
      *reinterpret_cast<ushort4*>(zv + 4 * i) = v4;
    }
    // no second barrier: next phase1 writes the OTHER buffer
  }
}

// ---------------------------------------------------------------- HOP: dst = A_hat * src ; XCD-affine bid swizzle
__global__ __launch_bounds__(256) void hop_kernel(
    const unsigned short* __restrict__ src, const int* __restrict__ cols,
    const float* __restrict__ wts, unsigned short* __restrict__ dst) {
  const int bid = blockIdx.x;
  const int r = bid & 7;
  const int t_ = bid >> 3;
  const int v = t_ & (NNODE - 1);
  const int g = t_ >> 9;
  const int b = g * 8 + r;
  const int tid = threadIdx.x;
  float acc[3][8];
  #pragma unroll
  for (int k = 0; k < 3; ++k)
    #pragma unroll
    for (int j = 0; j < 8; ++j) acc[k][j] = 0.f;
  for (int s = 0; s < NADJ; ++s) {
    const int col = cols[v * NADJ + s];
    const float w = wts[v * NADJ + s];
    const unsigned short* p = src + ((size_t)(b << 9) + col) * CT;
    #pragma unroll
    for (int k = 0; k < 2; ++k) {
      u16x8 u = *reinterpret_cast<const u16x8*>(p + 8 * (tid + 256 * k));
      #pragma unroll
      for (int j = 0; j < 8; ++j) acc[k][j] = fmaf(w, b2f(u[j]), acc[k][j]);
    }
    if (tid < NPAIR - 512) {
      u16x8 u = *reinterpret_cast<const u16x8*>(p + 8 * (tid + 512));
      #pragma unroll
      for (int j = 0; j < 8; ++j) acc[2][j] = fmaf(w, b2f(u[j]), acc[2][j]);
    }
  }
  unsigned short* dp = dst + ((size_t)(b << 9) + v) * CT;
  #pragma unroll
  for (int k = 0; k < 2; ++k) {
    u16x8 o;
    #pragma unroll
    for (int j = 0; j < 8; ++j) o[j] = f2b(acc[k][j]);
    *reinterpret_cast<u16x8*>(dp + 8 * (tid + 256 * k)) = o;
  }
  if (tid < NPAIR - 512) {
    u16x8 o;
    #pragma unroll
    for (int j = 0; j < 8; ++j) o[j] = f2b(acc[2][j]);
    *reinterpret_cast<u16x8*>(dp + 8 * (tid + 512)) = o;
  }
}

// ---------------------------------------------------------------- FIN: P = N0*z + N1*g1 + N2*g2 + mb + x_bf16 ; stats
__global__ __launch_bounds__(256) void fin_kernel(
    const unsigned short* __restrict__ z, const unsigned short* __restrict__ g1,
    const unsigned short* __restrict__ g2, const unsigned short* __restrict__ xbf,
    const unsigned short* __restrict__ pNA, const float* __restrict__ mb,
    unsigned short* __restrict__ P, float* __restrict__ stats) {
  const int b = blockIdx.y;
  const int tid = threadIdx.x;
  const int w = tid >> 6, l = tid & 63;
  const int jc = l & 31, h = l >> 5;
  const int v = blockIdx.x * 4 + w;

  bf16x8 nA[3][2];
  #pragma unroll
  for (int which = 0; which < 3; ++which)
    #pragma unroll
    for (int s = 0; s < 2; ++s) {
      nA[which][s] = *reinterpret_cast<const bf16x8*>(
          pNA + (((which * 2 + s) << 6) + l) * 8);
      pin(nA[which][s]);
    }
  float mbr[16];
  #pragma unroll
  for (int r = 0; r < 16; ++r) {
    const int co = (r & 3) + 8 * (r >> 2) + 4 * h;
    mbr[r] = mb[co];
  }

  const size_t base = (size_t)(b << 9) + v;
  const unsigned short* zs_ = z + base * CT;
  const unsigned short* g1s = g1 + base * CT;
  const unsigned short* g2s = g2 + base * CT;
  const unsigned short* xres = xbf + (size_t)(b * NNODE + v) * (XROWS * NC) + 12 * NC;
  unsigned short* Ps = P + base * CT;
  float st1 = 0.f, st2 = 0.f;

  #pragma unroll
  for (int tile = 0; tile < 5; ++tile) {
    const int t = tile * 32 + jc;
    const int off = t * NC + h * 8;
    f32x16 acc;
    #pragma unroll
    for (int r = 0; r < 16; ++r) acc[r] = 0.f;
    {
      bf16x8 b0 = *reinterpret_cast<const bf16x8*>(zs_ + off);
      bf16x8 b1 = *reinterpret_cast<const bf16x8*>(zs_ + off + 16);
      acc = __builtin_amdgcn_mfma_f32_32x32x16_bf16(nA[0][0], b0, acc, 0, 0, 0);
      acc = __builtin_amdgcn_mfma_f32_32x32x16_bf16(nA[0][1], b1, acc, 0, 0, 0);
    }
    {
      bf16x8 b0 = *reinterpret_cast<const bf16x8*>(g1s + off);
      bf16x8 b1 = *reinterpret_cast<const bf16x8*>(g1s + off + 16);
      acc = __builtin_amdgcn_mfma_f32_32x32x16_bf16(nA[1][0], b0, acc, 0, 0, 0);
      acc = __builtin_amdgcn_mfma_f32_32x32x16_bf16(nA[1][1], b1, acc, 0, 0, 0);
    }
    {
      bf16x8 b0 = *reinterpret_cast<const bf16x8*>(g2s + off);
      bf16x8 b1 = *reinterpret_cast<const bf16x8*>(g2s + off + 16);
      acc = __builtin_amdgcn_mfma_f32_32x32x16_bf16(nA[2][0], b0, acc, 0, 0, 0);
      acc = __builtin_amdgcn_mfma_f32_32x32x16_bf16(nA[2][1], b1, acc, 0, 0, 0);
    }
    if (t < NTO) {
      u16x4 xu[4];
      #pragma unroll
      for (int g = 0; g < 4; ++g)
        xu[g] = *reinterpret_cast<const u16x4*>(xres + t * NC + 4 * h + 8 * g);
      #pragma unroll
      for (int r = 0; r < 16; ++r) {
        const int co = (r & 3) + 8 * (r >> 2) + 4 * h;
        const float xr = b2f(xu[r >> 2][r & 3]);
        const float val = acc[r] + mbr[r] + xr;
        Ps[co * NTO + t] = f2b(val);
        st1 += val;
        st2 += val * val;
      }
    }
  }
  #pragma unroll
  for (int off = 32; off >= 1; off >>= 1) {
    st1 += __shfl_down(st1, off);
    st2 += __shfl_down(st2, off);
  }
  __shared__ float r1[4], r2[4];
  if ((tid & 63) == 0) { r1[w] = st1; r2[w] = st2; }
  __syncthreads();
  if (tid == 0) {   // b uniform per block
    atomicAdd(&stats[b * 2], r1[0] + r1[1] + r1[2] + r1[3]);
    atomicAdd(&stats[b * 2 + 1], r2[0] + r2[1] + r2[2] + r2[3]);
  }
}

// ---------------------------------------------------------------- LN: thread=(v,co,q), b INNER loop (lnw/lnb read once)
__global__ __launch_bounds__(256) void ln_kernel(
    const unsigned short* __restrict__ P, float* __restrict__ out,
    const float* __restrict__ lnw, const float* __restrict__ lnb,
    const int* __restrict__ idx, const float* __restrict__ stats) {
  const int i = blockIdx.x * 256 + threadIdx.x;   // over NNODE*NC*NQ
  const int q = i % NQ;
  const int r = i / NQ;
  const int co = r % NC;
  const int v = r / NC;
  const int iv = idx[v];
  const int lb = (co * NNODE + iv) * NTO + 4 * q;
  const float4 w = *reinterpret_cast<const float4*>(lnw + lb);
  const float4 bb = *reinterpret_cast<const float4*>(lnb + lb);
  const float invM = 1.0f / (float)(NC * NNODE * NTO);
  const int poff = (v * NC + co) * NTO + 4 * q;   // within-b P offset
  const int ooff = (co * NNODE + v) * NTO + 4 * q;
  for (int b = 0; b < NB; ++b) {
    const float mean = stats[b * 2] * invM;
    const float var = stats[b * 2 + 1] * invM - mean * mean;
    const float rs = rsqrtf(var + 1e-5f);
    ushort4 u = *reinterpret_cast<const ushort4*>(P + (size_t)b * (NNODE * CT) + poff);
    float4 o;
    o.x = (b2f(u.x) - mean) * rs * w.x + bb.x;
    o.y = (b2f(u.y) - mean) * rs * w.y + bb.y;
    o.z = (b2f(u.z) - mean) * rs * w.z + bb.z;
    o.w = (b2f(u.w) - mean) * rs * w.w + bb.w;
    *reinterpret_cast<float4*>(out + (size_t)b * (NC * NNODE * NTO) + ooff) = o;
  }
}

// ---------------------------------------------------------------- launch
extern "C" void kernel_launch(void* const* d_in, const int* in_sizes, int n_in,
                              void* d_out, int out_size, void* d_ws, size_t ws_size,
                              hipStream_t stream) {
  const float* x    = (const float*)d_in[0];
  const int*   idx  = (const int*)d_in[1];
  const float* emb1 = (const float*)d_in[2];
  const float* emb2 = (const float*)d_in[3];
  const float* W1   = (const float*)d_in[4];
  const float* b1   = (const float*)d_in[5];
  const float* W2   = (const float*)d_in[6];
  const float* b2   = (const float*)d_in[7];
  const float* mlp_w = (const float*)d_in[24];
  const float* mlp_b = (const float*)d_in[25];
  const float* ln_w = (const float*)d_in[26];
  const float* ln_b = (const float*)d_in[27];

  char* ws = (char*)d_ws;
  float* n1    = (float*)(ws);
  float* n2    = (float*)(ws + (128 << 10));
  int*   cols  = (int*)  (ws + (256 << 10));
  float* wts   = (float*)(ws + (320 << 10));
  float* stats = (float*)(ws + (384 << 10));
  unsigned short* pA = (unsigned short*)(ws + (400 << 10));    // 28,672 B
  float* pBias = (float*)(ws + (440 << 10));                   // 8,192 B
  unsigned short* pNA = (unsigned short*)(ws + (456 << 10));   // 6,144 B
  unsigned short* xbf = (unsigned short*)(ws + (512 << 10));   // 184.5 MB (live thru fin)
  const size_t xbf_elems = (size_t)NB * NNODE * XROWS * NC;
  const size_t slab_elems = (size_t)NB * NNODE * CT;           // 163 MB each
  unsigned short* z  = xbf + xbf_elems;
  unsigned short* g1 = z + slab_elems;
  unsigned short* g2 = g1 + slab_elems;
  unsigned short* P  = g2 + slab_elems;                        // separate 163 MB

  ZParams zp;
  for (int k = 0; k < 4; ++k) {
    zp.fw[k] = (const float*)d_in[8 + 2 * k];
    zp.fb[k] = (const float*)d_in[9 + 2 * k];
    zp.gw[k] = (const float*)d_in[16 + 2 * k];
    zp.gb[k] = (const float*)d_in[17 + 2 * k];
  }

  hipMemsetAsync(stats, 0, 2 * NB * sizeof(float), stream);
  g1_kernel<<<NNODE, 128, 0, stream>>>(emb1, emb2, W1, b1, W2, b2, idx, n1, n2);
  g2_kernel<<<NNODE, 256, 0, stream>>>(n1, n2, cols, wts);
  pack_kernel<<<76, 256, 0, stream>>>(zp, mlp_w, pA, pBias, pNA);
  xprep_kernel<<<dim3(NNODE, NB), 256, 0, stream>>>(x, xbf);
  conv_kernel<<<dim3(NNODE / NPB, NB), 256, 0, stream>>>(xbf, pA, pBias, z);
  hop_kernel<<<NB * NNODE, 256, 0, stream>>>(z, cols, wts, g1);
  hop_kernel<<<NB * NNODE, 256, 0, stream>>>(g1, cols, wts, g2);
  fin_kernel<<<dim3(NNODE / 4, NB), 256, 0, stream>>>(z, g1, g2, xbf, pNA, mlp_b,
                                                      P, stats);
  ln_kernel<<<NNODE * NC * NQ / 256, 256, 0, stream>>>(P, (float*)d_out, ln_w,
                                                       ln_b, idx, stats);
}